// Round 10
// baseline (131.705 us; speedup 1.0000x reference)
//
#include <hip/hip_runtime.h>

// GraphSAGE fused layer: out[B,128] = relu(concat(feat[nodes], mean_s feat[neigh])[B,256] @ W[256,128])
// B=50000, S=10, D=128, H=128. fp32 in/out; bf16 MFMA (threshold allows bf16).
//
// R10: wave-per-row gather with scalar bases. R6/R7/R9 showed the gather is
// bound by loads-in-flight per wave (compiler caps VGPR load batches at ~5).
// Now b is readfirstlane-uniform -> 11 indices are SMEM scalar loads, and the
// 11 feature-row loads are global_load_dwordx2 with SGPR base + shared lane
// voffset: 11 independent loads in ~22 data VGPRs, all in one waitcnt shadow.
// Wave covers a full 512 B row per instruction (8 lines/instr). 4 rows/wave,
// 32 rows/block; MFMA phase identical to R6/R9 (proven).

typedef __attribute__((ext_vector_type(8))) short bf16x8;   // 8 bf16 (4 VGPRs)
typedef __attribute__((ext_vector_type(4))) float f32x4;    // MFMA C/D frag

__device__ __forceinline__ unsigned short f2bf(float x) {
  unsigned int u = __float_as_uint(x);
  u += 0x7fffu + ((u >> 16) & 1u);
  return (unsigned short)(u >> 16);
}
__device__ __forceinline__ unsigned int pack2bf(float lo, float hi) {
  return (unsigned int)f2bf(lo) | ((unsigned int)f2bf(hi) << 16);
}

// W [K=256][H=128] fp32 row-major -> Wt [H=128][K=256] bf16 (once, to ws).
__global__ void sage_prep_wt(const float* __restrict__ W,
                             unsigned short* __restrict__ Wt) {
  int tid = blockIdx.x * blockDim.x + threadIdx.x;   // 0..8191 (float4 units)
  float4 v = ((const float4*)W)[tid];
  int flat = tid << 2;
  int k = flat >> 7;          // / H
  int h = flat & 127;         // % H
  Wt[(h + 0) * 256 + k] = f2bf(v.x);
  Wt[(h + 1) * 256 + k] = f2bf(v.y);
  Wt[(h + 2) * 256 + k] = f2bf(v.z);
  Wt[(h + 3) * 256 + k] = f2bf(v.w);
}

__global__ __launch_bounds__(512, 6)
void sage_fused7(const int* __restrict__ nodes,
                 const int* __restrict__ neigh,
                 const float* __restrict__ feat,
                 const unsigned short* __restrict__ Wt,
                 float* __restrict__ out, int B)
{
  constexpr int K = 256, H = 128, S = 10;
  constexpr int TILE = 32;
  constexpr int STR = K + 8;                   // 264 elems = 528 B rows (bank shift 4)
  __shared__ unsigned short Clds[TILE * STR];  // 16.9 KB

  const int t = threadIdx.x;
  const int lane = t & 63;
  // Force wave-uniformity so index loads become SMEM and feature-load bases
  // become SGPR pairs (saddr form: 1 shared voffset + 2 data VGPRs per load).
  const int wave = __builtin_amdgcn_readfirstlane(t >> 6);   // 0..7
  const int block0 = blockIdx.x * TILE;

  // ---- Phase 1: one wave per output row, 4 rows per wave ----
#pragma unroll
  for (int i = 0; i < 4; ++i) {
    const int r = wave * 4 + i;                // 0..31 (uniform)
    const int b = block0 + r;                  // uniform
    unsigned short* crow = &Clds[r * STR];
    if (b < B) {
      // 11 scalar indices (SMEM loads, wave-uniform addresses).
      const long nb = (long)b * S;
      const int i0 = nodes[b];
      int nx[S];
#pragma unroll
      for (int s = 0; s < S; ++s) nx[s] = neigh[nb + s];

      // 11 independent row loads: lane covers feature cols 2*lane, 2*lane+1.
      const float2 self = *(const float2*)(feat + (long)i0 * 128 + lane * 2);
      float2 v[S];
#pragma unroll
      for (int s = 0; s < S; ++s)
        v[s] = *(const float2*)(feat + (long)nx[s] * 128 + lane * 2);

      float sx = 0.f, sy = 0.f;
#pragma unroll
      for (int s = 0; s < S; ++s) { sx += v[s].x; sy += v[s].y; }

      // self half [0,128), mean half [128,256); 4 B/lane stride -> 2-way (free).
      *(unsigned int*)&crow[2 * lane]       = pack2bf(self.x, self.y);
      *(unsigned int*)&crow[128 + 2 * lane] = pack2bf(sx * 0.1f, sy * 0.1f);
    } else {
      *(unsigned int*)&crow[2 * lane]       = 0u;
      *(unsigned int*)&crow[128 + 2 * lane] = 0u;
    }
  }
  __syncthreads();
  __builtin_amdgcn_sched_barrier(0);   // keep Wt loads out of phase-1 lifetime

  // ---- Phase 2: 8 waves x (32 rows x 16 cols) MFMA (same as R6/R9) ----
  const int m    = lane & 15;
  const int quad = lane >> 4;
  const int cbase = wave * 16;      // 8 waves x 16 = 128 cols

  bf16x8 bfrag[8];
#pragma unroll
  for (int ks = 0; ks < 8; ++ks)
    bfrag[ks] = *(const bf16x8*)&Wt[(cbase + m) * K + ks * 32 + quad * 8];

  f32x4 acc0 = {0.f, 0.f, 0.f, 0.f};
  f32x4 acc1 = {0.f, 0.f, 0.f, 0.f};
#pragma unroll
  for (int ks = 0; ks < 8; ++ks) {
    const int koff = ks * 32 + quad * 8;
    bf16x8 a0 = *(const bf16x8*)&Clds[(m     ) * STR + koff];
    bf16x8 a1 = *(const bf16x8*)&Clds[(16 + m) * STR + koff];
    acc0 = __builtin_amdgcn_mfma_f32_16x16x32_bf16(a0, bfrag[ks], acc0, 0, 0, 0);
    acc1 = __builtin_amdgcn_mfma_f32_16x16x32_bf16(a1, bfrag[ks], acc1, 0, 0, 0);
  }

  // C/D layout: col = lane&15, row = quad*4 + reg (verified m89/m91)
#pragma unroll
  for (int reg = 0; reg < 4; ++reg) {
    const int row0 = quad * 4 + reg;
    const int gb0 = block0 + row0;
    const int gb1 = gb0 + 16;
    if (gb0 < B) out[(size_t)gb0 * H + cbase + m] = fmaxf(acc0[reg], 0.0f);
    if (gb1 < B) out[(size_t)gb1 * H + cbase + m] = fmaxf(acc1[reg], 0.0f);
  }
}

extern "C" void kernel_launch(void* const* d_in, const int* in_sizes, int n_in,
                              void* d_out, int out_size, void* d_ws, size_t ws_size,
                              hipStream_t stream) {
  const int*   nodes = (const int*)d_in[0];
  const int*   neigh = (const int*)d_in[1];
  const float* feat  = (const float*)d_in[2];
  const float* W     = (const float*)d_in[3];
  float*       out   = (float*)d_out;
  const int B = in_sizes[0];                       // 50000

  unsigned short* Wt = (unsigned short*)d_ws;      // 64 KB
  sage_prep_wt<<<32, 256, 0, stream>>>(W, Wt);
  const int grid = (B + 31) / 32;                  // 1563
  sage_fused7<<<grid, 512, 0, stream>>>(nodes, neigh, feat, Wt, out, B);
}